// Round 3
// baseline (179.655 us; speedup 1.0000x reference)
//
#include <hip/hip_runtime.h>

// IGN 2->2 dense layer, N=4, M=256, D=32, S=32, fp32.
// out[n,i,j,s] = sum_d (C10[d,s]*in[n,i,j,d] + C11[d,s]*in[n,j,i,d])
//              + RW[n,i,s] + CW[n,j,s] + (i==j)*DW[n,i,s]
// with RW/CW/DW precomputed from rows/cols/diag reductions and coeffs.

#define NN 4
#define MM 256
#define DD 32
#define SS 32

// ---- workspace layout (float offsets) ----
#define WS_ROWS   0          // [N*M*D]
#define WS_COLS   32768      // [N*M*D]
#define WS_DIAG   65536      // [N*M*D]
#define WS_RW     98304      // [N*M*S]
#define WS_CW     131072     // [N*M*S]
#define WS_DW     163840     // [N*M*S]
#define WS_SD     196608     // [N*D]
#define WS_TOT    196864     // [N*D]
#define WS_C10    197120     // [D*S]
#define WS_C11    198144     // [D*S]
// end: 199168 floats = 796672 bytes

// Kernel 1: rows[n,i,d] = sum_j in[n,i,j,d]; cols[n,j,d] = sum_i in[n,i,j,d];
// diag[n,i,d] = in[n,i,i,d].  grid = 2*N*M blocks of 256.
__global__ __launch_bounds__(256) void k_reduce(const float* __restrict__ in,
                                                float* __restrict__ ws) {
    float* rows = ws + WS_ROWS;
    float* cols = ws + WS_COLS;
    float* diagv = ws + WS_DIAG;
    int blk = blockIdx.x;
    bool do_cols = blk >= NN * MM;
    int nm = do_cols ? blk - NN * MM : blk;   // n*M + (i or j)
    int n = nm >> 8;
    int ij = nm & 255;
    int t = threadIdx.x;
    int d = t & 31, g = t >> 5;               // 8 accumulation groups
    float acc = 0.f;
    if (!do_cols) {
        const float* base = in + ((size_t)nm * MM) * DD + d;
        for (int j = g; j < MM; j += 8) acc += base[(size_t)j * DD];
    } else {
        const float* base = in + ((size_t)n * MM * MM + ij) * DD + d;
        for (int r = g; r < MM; r += 8) acc += base[(size_t)r * MM * DD];
    }
    __shared__ float red[256];
    red[t] = acc;
    __syncthreads();
    if (t < 32) {
        float s = 0.f;
        #pragma unroll
        for (int g2 = 0; g2 < 8; ++g2) s += red[g2 * 32 + t];
        if (!do_cols) {
            rows[nm * DD + t] = s;
            diagv[nm * DD + t] = in[(((size_t)nm) * MM + ij) * DD + t];
        } else {
            cols[nm * DD + t] = s;
        }
    }
}

// Kernel 2: sd[n,d], tot[n,d]; pack C10/C11.  grid = 2 blocks of 256.
__global__ __launch_bounds__(256) void k_small(const float* __restrict__ coeffs,
                                               float* __restrict__ ws) {
    if (blockIdx.x == 0) {
        int t = threadIdx.x;
        if (t < NN * DD) {
            int n = t >> 5, d = t & 31;
            const float* diagv = ws + WS_DIAG;
            const float* rows = ws + WS_ROWS;
            float s1 = 0.f, s2 = 0.f;
            for (int i = 0; i < MM; ++i) {
                s1 += diagv[(n * MM + i) * DD + d];
                s2 += rows[(n * MM + i) * DD + d];
            }
            ws[WS_SD + t] = s1;
            ws[WS_TOT + t] = s2;
        }
    } else {
        for (int idx = threadIdx.x; idx < DD * SS; idx += blockDim.x) {
            ws[WS_C10 + idx] = coeffs[idx * 15 + 9];    // op10: x
            ws[WS_C11 + idx] = coeffs[idx * 15 + 10];   // op11: x^T
        }
    }
}

// Kernel 3: RW/CW/DW.  grid = N*M*S/256 = 128 blocks of 256; thread -> (n,i,s).
__global__ __launch_bounds__(256) void k_aux(const float* __restrict__ coeffs,
                                             const float* __restrict__ diag_bias,
                                             const float* __restrict__ all_bias,
                                             float* __restrict__ ws) {
    int idx = blockIdx.x * blockDim.x + threadIdx.x;   // over N*M*S
    int s = idx & 31;
    int nm = idx >> 5;                                  // n*M + i
    int n = nm >> 8;
    const float* rows = ws + WS_ROWS;
    const float* cols = ws + WS_COLS;
    const float* diagv = ws + WS_DIAG;
    const float inv_m = 1.0f / MM;
    const float inv_m2 = inv_m * inv_m;
    float u = 0.f, v = 0.f, dgacc = 0.f, w = 0.f;
    for (int d = 0; d < DD; ++d) {
        const float* c = coeffs + (d * SS + s) * 15;
        float r = rows[nm * DD + d];
        float cl = cols[nm * DD + d];
        float dv = diagv[nm * DD + d];
        float sdv = ws[WS_SD + n * DD + d];
        float totv = ws[WS_TOT + n * DD + d];
        // i-dependent, all j: op6 cols_i/m, op7 rows_i/m, op12 diag_i
        u += c[5] * cl * inv_m + c[6] * r * inv_m + c[11] * dv;
        // j-dependent: op8 cols_j/m, op9 rows_j/m, op13 diag_j
        v += c[7] * cl * inv_m + c[8] * r * inv_m + c[12] * dv;
        // diagonal-only: op1 diag_i, op2 sd/m, op3 rows_i/m, op4 cols_i/m, op5 tot/m^2
        dgacc += c[0] * dv + c[1] * sdv * inv_m + c[2] * r * inv_m
               + c[3] * cl * inv_m + c[4] * totv * inv_m2;
        // constant: op14 sd/m, op15 tot/m^2
        w += c[13] * sdv * inv_m + c[14] * totv * inv_m2;
    }
    ws[WS_RW + idx] = u + w + all_bias[s];
    ws[WS_CW + idx] = v;
    ws[WS_DW + idx] = dgacc + diag_bias[s];
}

// Kernel 4: main.  grid = N*(M/16)*(M/16) = 1024 blocks of 256; thread -> one (i,j).
__global__ __launch_bounds__(256) void k_main(const float* __restrict__ in,
                                              const float* __restrict__ ws,
                                              float* __restrict__ out) {
    int b = blockIdx.x;
    int tjb = b & 15;
    int tib = (b >> 4) & 15;
    int n = b >> 8;
    int tj = threadIdx.x & 15, ti = threadIdx.x >> 4;
    int i = tib * 16 + ti, j = tjb * 16 + tj;

    const float* RW = ws + WS_RW;
    const float* CW = ws + WS_CW;
    const float* DW = ws + WS_DW;
    const float* c10 = ws + WS_C10;   // [D][S], uniform -> scalar loads
    const float* c11 = ws + WS_C11;

    float acc[SS];
    {
        const float4* rw = (const float4*)(RW + (n * MM + i) * SS);
        const float4* cw = (const float4*)(CW + (n * MM + j) * SS);
        #pragma unroll
        for (int q = 0; q < 8; ++q) {
            float4 a = rw[q], bq = cw[q];
            acc[q * 4 + 0] = a.x + bq.x;
            acc[q * 4 + 1] = a.y + bq.y;
            acc[q * 4 + 2] = a.z + bq.z;
            acc[q * 4 + 3] = a.w + bq.w;
        }
        if (i == j) {
            const float4* dw = (const float4*)(DW + (n * MM + i) * SS);
            #pragma unroll
            for (int q = 0; q < 8; ++q) {
                float4 dq = dw[q];
                acc[q * 4 + 0] += dq.x;
                acc[q * 4 + 1] += dq.y;
                acc[q * 4 + 2] += dq.z;
                acc[q * 4 + 3] += dq.w;
            }
        }
    }

    const float4* A = (const float4*)(in + (((size_t)(n * MM + i)) * MM + j) * DD);
    const float4* B = (const float4*)(in + (((size_t)(n * MM + j)) * MM + i) * DD);
    #pragma unroll
    for (int dq = 0; dq < 8; ++dq) {
        float4 a4 = A[dq];
        float4 b4 = B[dq];
        const float* ca = c10 + dq * 4 * SS;
        const float* cb = c11 + dq * 4 * SS;
        #pragma unroll
        for (int r = 0; r < 4; ++r) {
            float av = (r == 0) ? a4.x : (r == 1) ? a4.y : (r == 2) ? a4.z : a4.w;
            float bv = (r == 0) ? b4.x : (r == 1) ? b4.y : (r == 2) ? b4.z : b4.w;
            #pragma unroll
            for (int s = 0; s < SS; ++s) {
                acc[s] = fmaf(av, ca[r * SS + s], acc[s]);
                acc[s] = fmaf(bv, cb[r * SS + s], acc[s]);
            }
        }
    }

    float4* o = (float4*)(out + (((size_t)(n * MM + i)) * MM + j) * SS);
    #pragma unroll
    for (int q = 0; q < 8; ++q) {
        o[q] = make_float4(acc[q * 4 + 0], acc[q * 4 + 1], acc[q * 4 + 2], acc[q * 4 + 3]);
    }
}

extern "C" void kernel_launch(void* const* d_in, const int* in_sizes, int n_in,
                              void* d_out, int out_size, void* d_ws, size_t ws_size,
                              hipStream_t stream) {
    const float* in = (const float*)d_in[0];
    // d_in[1] = mask (all-ones, unused by the reference math)
    const float* coeffs = (const float*)d_in[2];
    const float* diag_bias = (const float*)d_in[3];
    const float* all_bias = (const float*)d_in[4];
    float* out = (float*)d_out;
    float* ws = (float*)d_ws;

    k_reduce<<<2 * NN * MM, 256, 0, stream>>>(in, ws);
    k_small<<<2, 256, 0, stream>>>(coeffs, ws);
    k_aux<<<(NN * MM * SS) / 256, 256, 0, stream>>>(coeffs, diag_bias, all_bias, ws);
    k_main<<<NN * 16 * 16, 256, 0, stream>>>(in, ws, out);
}

// Round 5
// 146.679 us; speedup vs baseline: 1.2248x; 1.2248x over previous
//
#include <hip/hip_runtime.h>

// IGN 2->2 dense layer, N=4, M=256, D=32, S=32, fp32.
// out[n,i,j,s] = sum_d (C10[d,s]*in[n,i,j,d] + C11[d,s]*in[n,j,i,d])
//              + RW[n,i,s] + CW[n,j,s] + (i==j)*DW[n,i,s]

#define NN 4
#define MM 256
#define DD 32
#define SS 32

// ---- workspace layout (float offsets) ----
#define WS_ROWS   0          // [N*M*D]  = 32768
#define WS_COLSA  32768      // [N*M*D]  partial cols, i in [0,128)
#define WS_COLSB  65536      // [N*M*D]  partial cols, i in [128,256)
#define WS_DIAG   98304      // [N*M*D]
#define WS_RW     131072     // [N*M*S]
#define WS_CW     163840     // [N*M*S]
#define WS_DW     196608     // [N*M*S]
#define WS_SD     229376     // [N*D] = 128   (atomic-accumulated; memset to 0 first)
#define WS_TOT    229504     // [N*D] = 128   (atomic-accumulated; memset to 0 first)
#define WS_CPACK  229632     // [15][D*S] = 15360  packed coeffs, plane-major
// end: 244992 floats = 979968 bytes

// Kernel 1: cols partials (blocks 0..255), rows+diag+sd/tot (blocks 256..1279),
// coeff pack (block 1280).
__global__ __launch_bounds__(256) void k_reduce(const float* __restrict__ in,
                                                const float* __restrict__ coeffs,
                                                float* __restrict__ ws) {
    int blk = blockIdx.x;
    int t = threadIdx.x;
    if (blk < 256) {
        // cols[n,j,d] partial over half the i-range; 8-column strip per block.
        int n = blk >> 6;
        int rem = blk & 63;
        int half = rem >> 5;          // 0: i<128 -> COLSA, 1: i>=128 -> COLSB
        int jt = rem & 31;
        int j = jt * 8 + (t >> 5);
        int d = t & 31;
        const float* base = in + ((size_t)n * MM * MM + j) * DD + d
                               + (size_t)half * 128 * MM * DD;
        float acc = 0.f;
        #pragma unroll 8
        for (int i = 0; i < 128; ++i) acc += base[(size_t)i * MM * DD];
        float* dst = ws + (half ? WS_COLSB : WS_COLSA);
        dst[(n * MM + j) * DD + d] = acc;
    } else if (blk < 256 + NN * MM) {
        int nm = blk - 256;           // n*M + i
        int n = nm >> 8;
        int ii = nm & 255;
        int d = t & 31, g = t >> 5;   // 8 accumulation groups over j
        const float* base = in + (size_t)nm * MM * DD + d;
        float acc = 0.f;
        for (int j = g; j < MM; j += 8) acc += base[(size_t)j * DD];
        __shared__ float red[256];
        red[t] = acc;
        __syncthreads();
        if (t < 32) {
            float s = 0.f;
            #pragma unroll
            for (int g2 = 0; g2 < 8; ++g2) s += red[g2 * 32 + t];
            ws[WS_ROWS + nm * DD + t] = s;
            float dv = in[((size_t)nm * MM + ii) * DD + t];
            ws[WS_DIAG + nm * DD + t] = dv;
            atomicAdd(ws + WS_TOT + n * DD + t, s);   // tot[n,d] = sum_i rows
            atomicAdd(ws + WS_SD + n * DD + t, dv);   // sd[n,d]  = sum_i diag
        }
    } else {
        // pack coeffs [D*S,15] -> [15][D*S]
        for (int idx = t; idx < 15 * DD * SS; idx += 256) {
            int plane = idx >> 10;    // /1024
            int ds = idx & 1023;
            ws[WS_CPACK + plane * (DD * SS) + ds] = coeffs[ds * 15 + plane];
        }
    }
}

// Kernel 2: RW/CW/DW.  grid = N*M*S/256 = 128 blocks; thread -> (n,i,s).
__global__ __launch_bounds__(256) void k_aux(const float* __restrict__ diag_bias,
                                             const float* __restrict__ all_bias,
                                             float* __restrict__ ws) {
    int idx = blockIdx.x * blockDim.x + threadIdx.x;   // over N*M*S
    int s = idx & 31;
    int nm = idx >> 5;                                  // n*M + i
    int n = nm >> 8;
    const float inv_m = 1.0f / MM;
    const float inv_m2 = inv_m * inv_m;
    float u = 0.f, v = 0.f, dgacc = 0.f, w = 0.f;
    for (int d = 0; d < DD; ++d) {
        const float* cp = ws + WS_CPACK + d * SS + s;   // plane stride D*S
        float r = ws[WS_ROWS + nm * DD + d];
        float cl = ws[WS_COLSA + nm * DD + d] + ws[WS_COLSB + nm * DD + d];
        float dv = ws[WS_DIAG + nm * DD + d];
        float sdv = ws[WS_SD + n * DD + d];
        float totv = ws[WS_TOT + n * DD + d];
        // i-dependent, all j: op6 cols_i/m, op7 rows_i/m, op12 diag_i
        u += cp[5 * 1024] * cl * inv_m + cp[6 * 1024] * r * inv_m + cp[11 * 1024] * dv;
        // j-dependent: op8 cols_j/m, op9 rows_j/m, op13 diag_j
        v += cp[7 * 1024] * cl * inv_m + cp[8 * 1024] * r * inv_m + cp[12 * 1024] * dv;
        // diagonal-only: op1..op5
        dgacc += cp[0] * dv + cp[1 * 1024] * sdv * inv_m + cp[2 * 1024] * r * inv_m
               + cp[3 * 1024] * cl * inv_m + cp[4 * 1024] * totv * inv_m2;
        // constant: op14 sd/m, op15 tot/m^2
        w += cp[13 * 1024] * sdv * inv_m + cp[14 * 1024] * totv * inv_m2;
    }
    ws[WS_RW + idx] = u + w + all_bias[s];
    ws[WS_CW + idx] = v;
    ws[WS_DW + idx] = dgacc + diag_bias[s];
}

// Kernel 3: main.  grid = N*16*16 = 1024 blocks of 256; thread -> one (i,j).
// Loads staged into register arrays BEFORE the FMA phase for MLP.
__global__ __launch_bounds__(256, 2) void k_main(const float* __restrict__ in,
                                                 const float* __restrict__ ws,
                                                 float* __restrict__ out) {
    int b = blockIdx.x;
    int tjb = b & 15;
    int tib = (b >> 4) & 15;
    int n = b >> 8;
    int tj = threadIdx.x & 15, ti = threadIdx.x >> 4;
    int i = tib * 16 + ti, j = tjb * 16 + tj;

    const float4* A = (const float4*)(in + (((size_t)(n * MM + i)) * MM + j) * DD);
    const float4* B = (const float4*)(in + (((size_t)(n * MM + j)) * MM + i) * DD);

    // Stage all 16 input vectors (256B) in registers — 16 loads in flight.
    float4 av[8], bv[8];
    #pragma unroll
    for (int q = 0; q < 8; ++q) av[q] = A[q];
    #pragma unroll
    for (int q = 0; q < 8; ++q) bv[q] = B[q];

    const float4* rw = (const float4*)(ws + WS_RW + (n * MM + i) * SS);
    const float4* cw = (const float4*)(ws + WS_CW + (n * MM + j) * SS);
    float acc[SS];
    #pragma unroll
    for (int q = 0; q < 8; ++q) {
        float4 x = rw[q], y = cw[q];
        acc[q * 4 + 0] = x.x + y.x;
        acc[q * 4 + 1] = x.y + y.y;
        acc[q * 4 + 2] = x.z + y.z;
        acc[q * 4 + 3] = x.w + y.w;
    }
    if (i == j) {
        const float4* dw = (const float4*)(ws + WS_DW + (n * MM + i) * SS);
        #pragma unroll
        for (int q = 0; q < 8; ++q) {
            float4 dq = dw[q];
            acc[q * 4 + 0] += dq.x;
            acc[q * 4 + 1] += dq.y;
            acc[q * 4 + 2] += dq.z;
            acc[q * 4 + 3] += dq.w;
        }
    }

    const float* c10 = ws + WS_CPACK + 9 * (DD * SS);    // [D][S], uniform -> s_load
    const float* c11 = ws + WS_CPACK + 10 * (DD * SS);
    #pragma unroll
    for (int dq = 0; dq < 8; ++dq) {
        const float* ca = c10 + dq * 4 * SS;
        const float* cb = c11 + dq * 4 * SS;
        #pragma unroll
        for (int r = 0; r < 4; ++r) {
            float a = (r == 0) ? av[dq].x : (r == 1) ? av[dq].y : (r == 2) ? av[dq].z : av[dq].w;
            float bb = (r == 0) ? bv[dq].x : (r == 1) ? bv[dq].y : (r == 2) ? bv[dq].z : bv[dq].w;
            #pragma unroll
            for (int s = 0; s < SS; ++s) {
                acc[s] = fmaf(a, ca[r * SS + s], acc[s]);
                acc[s] = fmaf(bb, cb[r * SS + s], acc[s]);
            }
        }
    }

    float4* o = (float4*)(out + (((size_t)(n * MM + i)) * MM + j) * SS);
    #pragma unroll
    for (int q = 0; q < 8; ++q)
        o[q] = make_float4(acc[q * 4 + 0], acc[q * 4 + 1], acc[q * 4 + 2], acc[q * 4 + 3]);
}

extern "C" void kernel_launch(void* const* d_in, const int* in_sizes, int n_in,
                              void* d_out, int out_size, void* d_ws, size_t ws_size,
                              hipStream_t stream) {
    const float* in = (const float*)d_in[0];
    // d_in[1] = mask (all-ones, unused by the reference math)
    const float* coeffs = (const float*)d_in[2];
    const float* diag_bias = (const float*)d_in[3];
    const float* all_bias = (const float*)d_in[4];
    float* out = (float*)d_out;
    float* ws = (float*)d_ws;

    // zero the atomic accumulators sd/tot (256 floats)
    hipMemsetAsync((char*)d_ws + (size_t)WS_SD * 4, 0, 256 * sizeof(float), stream);
    k_reduce<<<256 + NN * MM + 1, 256, 0, stream>>>(in, coeffs, ws);
    k_aux<<<(NN * MM * SS) / 256, 256, 0, stream>>>(diag_bias, all_bias, ws);
    k_main<<<NN * 16 * 16, 256, 0, stream>>>(in, ws, out);
}